// Round 1
// baseline (384.165 us; speedup 1.0000x reference)
//
#include <hip/hip_runtime.h>

typedef unsigned short u16;
typedef __attribute__((ext_vector_type(8))) short s8v;           // bf16x8 MFMA frag
typedef __attribute__((ext_vector_type(8))) unsigned short us8;  // 16B copy vector
typedef __attribute__((ext_vector_type(4))) float f4v;           // MFMA acc frag

#define L2E 1.4426950408889634f
#define NEGBIG2 (-9.0e15f * 1.4426950408889634f)

typedef __attribute__((address_space(1))) void gvoid_t;
typedef __attribute__((address_space(3))) void lvoid_t;

__device__ __forceinline__ u16 f2bf(float f) {
  unsigned u = __builtin_bit_cast(unsigned, f);
  return (u16)((u + 0x7FFFu + ((u >> 16) & 1u)) >> 16);
}
__device__ __forceinline__ float bf2f(u16 h) {
  return __builtin_bit_cast(float, ((unsigned)h) << 16);
}
__device__ __forceinline__ f4v mfma16(s8v a, s8v b, f4v c) {
  return __builtin_amdgcn_mfma_f32_16x16x32_bf16(a, b, c, 0, 0, 0);
}
__device__ __forceinline__ float exp2fast(float x) {
#if __has_builtin(__builtin_amdgcn_exp2f)
  return __builtin_amdgcn_exp2f(x);
#else
  return exp2f(x);
#endif
}
// async global->LDS, 16B per lane; LDS dest = uniform base + lane*16
__device__ __forceinline__ void stage16(const u16* g, u16* lds_arr, int slot) {
#if __has_builtin(__builtin_amdgcn_global_load_lds)
  __builtin_amdgcn_global_load_lds((gvoid_t*)(g),
      (lvoid_t*)(lds_arr + (size_t)(slot & ~63) * 8), 16, 0, 0);
#else
  *(us8*)(lds_arr + (size_t)slot * 8) = *(const us8*)g;
#endif
}

// ---------------- prep kernels ----------------
__global__ __launch_bounds__(256) void prep_x(const float* __restrict__ x,
                                              u16* __restrict__ xb) {
  int i = (blockIdx.x * 256 + threadIdx.x) * 8;
  float4 v0 = *(const float4*)(x + i);
  float4 v1 = *(const float4*)(x + i + 4);
  us8 o;
  o[0] = f2bf(v0.x); o[1] = f2bf(v0.y); o[2] = f2bf(v0.z); o[3] = f2bf(v0.w);
  o[4] = f2bf(v1.x); o[5] = f2bf(v1.y); o[6] = f2bf(v1.z); o[7] = f2bf(v1.w);
  *(us8*)(xb + i) = o;
}

// W_heads [4][512][128] f32 -> Wt_all [512 cols][512 k] bf16 (col = h*128+f)
__global__ __launch_bounds__(256) void prep_wall(const float* __restrict__ W,
                                                 u16* __restrict__ Wt) {
  int idx = blockIdx.x * 256 + threadIdx.x;  // h*65536 + k*128 + f
  int h = idx >> 16, k = (idx >> 7) & 511, f = idx & 127;
  Wt[(size_t)(h * 128 + f) * 512 + k] = f2bf(W[idx]);
}
// W_out [512][256] f32 -> Wt_out [256][512] bf16
__global__ __launch_bounds__(256) void prep_wout(const float* __restrict__ W,
                                                 u16* __restrict__ Wt) {
  int idx = blockIdx.x * 256 + threadIdx.x;  // k*256 + c
  int k = idx >> 8, c = idx & 255;
  Wt[(size_t)c * 512 + k] = f2bf(W[idx]);
}
// adj int32 [4][2048][2048] -> bitmask [4*2048][64 words]
__global__ __launch_bounds__(256) void prep_adj(const int* __restrict__ adj,
                                                unsigned* __restrict__ adjw) {
  int chunk = blockIdx.x * 4 + (threadIdx.x >> 6);
  int l = threadIdx.x & 63;
  int v = adj[(size_t)chunk * 64 + l];
  unsigned long long m = __ballot(v != 0);
  if (l == 0) {
    ((uint2*)adjw)[chunk] = make_uint2((unsigned)m, (unsigned)(m >> 32));
  }
}

// ---------------- GEMM: C^T = (A[M,512] @ B) stored as Ct[b][col][n] bf16 ----
// A row-major bf16, Bt = B^T [CO][512] bf16. 128x128 tile, BK=32, dbuf LDS.
__global__ __launch_bounds__(256) void gemm_bf16(const u16* __restrict__ A,
                                                 const u16* __restrict__ Bt,
                                                 u16* __restrict__ Ct, int CO) {
  const int K = 512, N = 2048;
  int m0 = blockIdx.x * 128;
  int n0 = blockIdx.y * 128;
  int t = threadIdx.x;
  int w = t >> 6, l = t & 63, lr = l & 15, lq = l >> 4;
  int wr = w >> 1, wc = w & 1;
  __shared__ u16 As[2][128 * 32];
  __shared__ u16 Bs[2][128 * 32];
  f4v zero4 = {0.f, 0.f, 0.f, 0.f};
  f4v acc[4][4];
#pragma unroll
  for (int i = 0; i < 4; ++i)
#pragma unroll
    for (int j = 0; j < 4; ++j) acc[i][j] = zero4;

  auto stage = [&](int buf, int kt) {
    int k0 = kt * 32;
    int row = t >> 2, ch = t & 3;
    stage16(A + (size_t)(m0 + row) * K + k0 + ch * 8, As[buf], t);
    stage16(Bt + (size_t)(n0 + row) * K + k0 + ch * 8, Bs[buf], t);
    int s2 = t + 256;
    row = s2 >> 2; ch = s2 & 3;
    stage16(A + (size_t)(m0 + row) * K + k0 + ch * 8, As[buf], s2);
    stage16(Bt + (size_t)(n0 + row) * K + k0 + ch * 8, Bs[buf], s2);
  };
  stage(0, 0);
  for (int kt = 0; kt < 16; ++kt) {
    __syncthreads();
    if (kt < 15) stage((kt + 1) & 1, kt + 1);
    const u16* as = As[kt & 1];
    const u16* bs = Bs[kt & 1];
    s8v af[4], bfr[4];
#pragma unroll
    for (int rf = 0; rf < 4; ++rf)
      af[rf] = *(const s8v*)&as[(wr * 64 + rf * 16 + lr) * 32 + lq * 8];
#pragma unroll
    for (int nf = 0; nf < 4; ++nf)
      bfr[nf] = *(const s8v*)&bs[(wc * 64 + nf * 16 + lr) * 32 + lq * 8];
#pragma unroll
    for (int rf = 0; rf < 4; ++rf)
#pragma unroll
      for (int nf = 0; nf < 4; ++nf)
        acc[rf][nf] = mfma16(af[rf], bfr[nf], acc[rf][nf]);
  }
  int bidx = m0 >> 11;
  int nr0 = m0 & 2047;
#pragma unroll
  for (int rf = 0; rf < 4; ++rf) {
#pragma unroll
    for (int nf = 0; nf < 4; ++nf) {
      int col = n0 + wc * 64 + nf * 16 + lr;
      int nr = nr0 + wr * 64 + rf * 16 + lq * 4;
      f4v a = acc[rf][nf];
      ushort4 v = make_ushort4(f2bf(a[0]), f2bf(a[1]), f2bf(a[2]), f2bf(a[3]));
      *(ushort4*)&Ct[((size_t)bidx * CO + col) * N + nr] = v;
    }
  }
}

// ---------------- f1/f2 (scaled by log2e) from Wh_t ----------------
__global__ __launch_bounds__(128) void fkern(const u16* __restrict__ Wht,
                                             const float* __restrict__ a,
                                             float* __restrict__ f1L,
                                             float* __restrict__ f2L, int COLS,
                                             int F) {
  const int N = 2048;
  int h = blockIdx.z, b = blockIdx.y;
  int n = blockIdx.x * 128 + threadIdx.x;
  const u16* colp = Wht + ((size_t)(b * COLS + h * F)) * N + n;
  const float* ah = a + h * 2 * F;
  float a1 = 0.f, a2 = 0.f;
  for (int c = 0; c < F; ++c) {
    float v = bf2f(colp[(size_t)c * N]);
    a1 = fmaf(v, ah[c], a1);
    a2 = fmaf(v, ah[F + c], a2);
  }
  f1L[(size_t)(h * 4 + b) * N + n] = a1 * L2E;
  f2L[(size_t)(h * 4 + b) * N + n] = a2 * L2E;
}

// ---------------- fused flash-GAT attention ----------------
// block = (b, 32-row i-tile); 4 waves split COLS; scores built analytically in
// the 16x16x32 A-frag layout; online softmax in exp2 domain; P@V via MFMA.
template <int COLS, int F, bool ELU>
__global__ __launch_bounds__(256) void attn_kernel(
    const u16* __restrict__ Wht, const float* __restrict__ f1L,
    const float* __restrict__ f2L, const unsigned* __restrict__ adjw,
    const float* __restrict__ mask, void* __restrict__ outp) {
  constexpr int CW = COLS / 4;
  constexpr int NF = CW / 16;
  constexpr int STJ = COLS / 64;
  const int N = 2048;
  int kb = blockIdx.x;
  int b = (kb & 7) >> 1;                            // XCD-aware: 2 XCDs per b
  int i0 = ((((kb >> 3) << 1) | (kb & 1))) * 32;
  int t = threadIdx.x;
  int w = t >> 6, l = t & 63, lr = l & 15, lq = l >> 4;
  int hw = (w * CW) / F;
  __shared__ u16 Vt[2][COLS * 32];

  const float* f1p = f1L + (size_t)(hw * 4 + b) * N + i0;
  float f1lo = f1p[lr], f1hi = f1p[lr + 16];
  const float* f2p = f2L + (size_t)(hw * 4 + b) * N;
  const unsigned* awlo_p = adjw + (size_t)(b * N + i0 + lr) * 64;
  const unsigned* awhi_p = adjw + (size_t)(b * N + i0 + lr + 16) * 64;

  float m_lo = -__builtin_inff(), m_hi = -__builtin_inff();
  float s_lo = 0.f, s_hi = 0.f;
  f4v zero4 = {0.f, 0.f, 0.f, 0.f};
  f4v acc[2][NF];
#pragma unroll
  for (int i = 0; i < 2; ++i)
#pragma unroll
    for (int j = 0; j < NF; ++j) acc[i][j] = zero4;

  auto stage = [&](int buf, int jt) {
    int j0 = jt * 32;
#pragma unroll
    for (int j = 0; j < STJ; ++j) {
      int slot = j * 256 + t;
      int c = slot >> 2, q = slot & 3;
      stage16(Wht + ((size_t)(b * COLS + c)) * N + j0 + q * 8, Vt[buf], slot);
    }
  };
  stage(0, 0);
  for (int jt = 0; jt < 64; ++jt) {
    __syncthreads();
    if (jt < 63) stage((jt + 1) & 1, jt + 1);
    int j0 = jt * 32;
    unsigned aw_lo = awlo_p[jt];
    unsigned aw_hi = awhi_p[jt];
    float4 fa = *(const float4*)&f2p[j0 + lq * 8];
    float4 fb = *(const float4*)&f2p[j0 + lq * 8 + 4];
    float f2arr[8] = {fa.x, fa.y, fa.z, fa.w, fb.x, fb.y, fb.z, fb.w};
    unsigned blo = (aw_lo >> (lq * 8)) & 0xFFu;
    unsigned bhi = (aw_hi >> (lq * 8)) & 0xFFu;
    float e_lo[8], e_hi[8];
#pragma unroll
    for (int e = 0; e < 8; ++e) {
      float s1 = f1lo + f2arr[e];
      float v1 = fmaxf(s1, 0.2f * s1);
      e_lo[e] = ((blo >> e) & 1u) ? v1 : NEGBIG2;
      float s2 = f1hi + f2arr[e];
      float v2 = fmaxf(s2, 0.2f * s2);
      e_hi[e] = ((bhi >> e) & 1u) ? v2 : NEGBIG2;
    }
    float mt_lo = e_lo[0], mt_hi = e_hi[0];
#pragma unroll
    for (int e = 1; e < 8; ++e) {
      mt_lo = fmaxf(mt_lo, e_lo[e]);
      mt_hi = fmaxf(mt_hi, e_hi[e]);
    }
    mt_lo = fmaxf(mt_lo, __shfl_xor(mt_lo, 16));
    mt_lo = fmaxf(mt_lo, __shfl_xor(mt_lo, 32));
    mt_hi = fmaxf(mt_hi, __shfl_xor(mt_hi, 16));
    mt_hi = fmaxf(mt_hi, __shfl_xor(mt_hi, 32));
    bool grow = (mt_lo > m_lo) || (mt_hi > m_hi);
    if (__any(grow)) {
      float mn_lo = fmaxf(m_lo, mt_lo), mn_hi = fmaxf(m_hi, mt_hi);
      float sc_lo = exp2fast(m_lo - mn_lo), sc_hi = exp2fast(m_hi - mn_hi);
      s_lo *= sc_lo; s_hi *= sc_hi;
      m_lo = mn_lo; m_hi = mn_hi;
      f4v s4lo, s4hi;
#pragma unroll
      for (int r = 0; r < 4; ++r) {
        s4lo[r] = __shfl(sc_lo, lq * 4 + r);
        s4hi[r] = __shfl(sc_hi, lq * 4 + r);
      }
#pragma unroll
      for (int nf = 0; nf < NF; ++nf) {
        acc[0][nf] *= s4lo;
        acc[1][nf] *= s4hi;
      }
    }
    float ps_lo = 0.f, ps_hi = 0.f;
    s8v pa_lo, pa_hi;
#pragma unroll
    for (int e = 0; e < 8; ++e) {
      float p1 = exp2fast(e_lo[e] - m_lo);
      float p2 = exp2fast(e_hi[e] - m_hi);
      ps_lo += p1; ps_hi += p2;
      pa_lo[e] = (short)f2bf(p1);
      pa_hi[e] = (short)f2bf(p2);
    }
    ps_lo += __shfl_xor(ps_lo, 16); ps_lo += __shfl_xor(ps_lo, 32);
    ps_hi += __shfl_xor(ps_hi, 16); ps_hi += __shfl_xor(ps_hi, 32);
    s_lo += ps_lo; s_hi += ps_hi;
    const u16* vb = Vt[jt & 1];
#pragma unroll
    for (int nf = 0; nf < NF; ++nf) {
      s8v bfr = *(const s8v*)&vb[(w * CW + nf * 16 + lr) * 32 + lq * 8];
      acc[0][nf] = mfma16(pa_lo, bfr, acc[0][nf]);
      acc[1][nf] = mfma16(pa_hi, bfr, acc[1][nf]);
    }
  }
  float is_lo = 1.f / s_lo, is_hi = 1.f / s_hi;
  f4v i4lo, i4hi;
#pragma unroll
  for (int r = 0; r < 4; ++r) {
    i4lo[r] = __shfl(is_lo, lq * 4 + r);
    i4hi[r] = __shfl(is_hi, lq * 4 + r);
  }
  if constexpr (ELU) {
    u16* xo = (u16*)outp;
#pragma unroll
    for (int nf = 0; nf < NF; ++nf) {
      int col = w * CW + nf * 16 + lr;
#pragma unroll
      for (int r = 0; r < 4; ++r) {
        {
          float v = acc[0][nf][r] * i4lo[r];
          v = v > 0.f ? v : exp2fast(v * L2E) - 1.f;
          xo[((size_t)(b * N + i0 + lq * 4 + r)) * COLS + col] = f2bf(v);
        }
        {
          float v = acc[1][nf][r] * i4hi[r];
          v = v > 0.f ? v : exp2fast(v * L2E) - 1.f;
          xo[((size_t)(b * N + i0 + 16 + lq * 4 + r)) * COLS + col] = f2bf(v);
        }
      }
    }
  } else {
    float* xo = (float*)outp;
    float4 mk_lo = *(const float4*)&mask[b * N + i0 + lq * 4];
    float4 mk_hi = *(const float4*)&mask[b * N + i0 + 16 + lq * 4];
    float ml[4] = {mk_lo.x, mk_lo.y, mk_lo.z, mk_lo.w};
    float mh[4] = {mk_hi.x, mk_hi.y, mk_hi.z, mk_hi.w};
#pragma unroll
    for (int nf = 0; nf < NF; ++nf) {
      int col = w * CW + nf * 16 + lr;
#pragma unroll
      for (int r = 0; r < 4; ++r) {
        xo[((size_t)(b * N + i0 + lq * 4 + r)) * COLS + col] =
            acc[0][nf][r] * i4lo[r] * ml[r];
        xo[((size_t)(b * N + i0 + 16 + lq * 4 + r)) * COLS + col] =
            acc[1][nf][r] * i4hi[r] * mh[r];
      }
    }
  }
}

// ---------------- pooling + final GEMM ----------------
__global__ __launch_bounds__(256) void pool1(const float* __restrict__ xout,
                                             const float* __restrict__ mask,
                                             float* __restrict__ pool,
                                             float* __restrict__ den) {
  int b = blockIdx.x >> 4, s = blockIdx.x & 15;
  int c = threadIdx.x;
  int n0 = s * 128;
  float acc = 0.f;
  for (int r = 0; r < 128; ++r)
    acc += xout[((size_t)(b * 2048 + n0 + r)) * 256 + c];
  atomicAdd(&pool[b * 256 + c], acc);
  if (c == 0) {
    float ms = 0.f;
    for (int r = 0; r < 128; ++r) ms += mask[b * 2048 + n0 + r];
    atomicAdd(&den[b], ms);
  }
}
__global__ __launch_bounds__(256) void pool2(const float* __restrict__ pool,
                                             const float* __restrict__ den,
                                             const float* __restrict__ Wp,
                                             const float* __restrict__ bp,
                                             float* __restrict__ out) {
  int b = blockIdx.x, f = threadIdx.x;
  __shared__ float pv[256];
  float inv = 1.f / (den[b] + 1e-10f);
  pv[f] = pool[b * 256 + f] * inv;
  __syncthreads();
  float acc = bp[f];
  for (int c = 0; c < 256; ++c) acc = fmaf(pv[c], Wp[c * 256 + f], acc);
  out[b * 256 + f] = fmaxf(acc, 0.f);
}

// ---------------- launcher ----------------
extern "C" void kernel_launch(void* const* d_in, const int* in_sizes, int n_in,
                              void* d_out, int out_size, void* d_ws,
                              size_t ws_size, hipStream_t stream) {
  (void)in_sizes; (void)n_in; (void)out_size; (void)ws_size;
  const float* x = (const float*)d_in[0];
  const int* adj = (const int*)d_in[1];
  const float* mask = (const float*)d_in[2];
  const float* Whds = (const float*)d_in[3];
  const float* ahds = (const float*)d_in[4];
  const float* Wout = (const float*)d_in[5];
  const float* aout = (const float*)d_in[6];
  const float* Wpool = (const float*)d_in[7];
  const float* bpool = (const float*)d_in[8];
  float* out = (float*)d_out;

  char* ws = (char*)d_ws;
  size_t off = 0;
  auto take = [&](size_t n) {
    char* p = ws + off;
    off += (n + 255) & ~(size_t)255;
    return p;
  };
  u16* xb = (u16*)take(8192ull * 512 * 2);
  u16* Wta = (u16*)take(512ull * 512 * 2);
  u16* Wto = (u16*)take(256ull * 512 * 2);
  unsigned* adjw = (unsigned*)take(4ull * 2048 * 64 * 4);
  u16* Wht = (u16*)take(4ull * 512 * 2048 * 2);
  float* f1a = (float*)take(4ull * 4 * 2048 * 4);
  float* f2a = (float*)take(4ull * 4 * 2048 * 4);
  u16* xcat = (u16*)take(8192ull * 512 * 2);
  u16* Wh2t = (u16*)take(4ull * 256 * 2048 * 2);
  float* f1b = (float*)take(4ull * 2048 * 4);
  float* f2b = (float*)take(4ull * 2048 * 4);
  float* pool = (float*)take(1024 * 4);
  float* den = (float*)take(256);

  prep_x<<<2048, 256, 0, stream>>>(x, xb);
  prep_wall<<<1024, 256, 0, stream>>>(Whds, Wta);
  prep_wout<<<512, 256, 0, stream>>>(Wout, Wto);
  prep_adj<<<65536, 256, 0, stream>>>(adj, adjw);
  gemm_bf16<<<dim3(64, 4), 256, 0, stream>>>(xb, Wta, Wht, 512);
  fkern<<<dim3(16, 4, 4), 128, 0, stream>>>(Wht, ahds, f1a, f2a, 512, 128);
  attn_kernel<512, 128, true><<<256, 256, 0, stream>>>(Wht, f1a, f2a, adjw,
                                                       nullptr, xcat);
  gemm_bf16<<<dim3(64, 2), 256, 0, stream>>>(xcat, Wto, Wh2t, 256);
  fkern<<<dim3(16, 4, 1), 128, 0, stream>>>(Wh2t, aout, f1b, f2b, 256, 256);
  attn_kernel<256, 256, false><<<256, 256, 0, stream>>>(Wh2t, f1b, f2b, adjw,
                                                        mask, out + 1024);
  hipMemsetAsync(pool, 0, 4096 + 256, stream);
  pool1<<<64, 256, 0, stream>>>(out + 1024, mask, pool, den);
  pool2<<<4, 256, 0, stream>>>(pool, den, Wpool, bpool, out);
}

// Round 2
// 242.677 us; speedup vs baseline: 1.5830x; 1.5830x over previous
//
#include <hip/hip_runtime.h>

typedef unsigned short u16;
typedef __attribute__((ext_vector_type(8))) short s8v;           // bf16x8 MFMA frag
typedef __attribute__((ext_vector_type(8))) unsigned short us8;  // 16B copy vector
typedef __attribute__((ext_vector_type(4))) float f4v;           // MFMA acc frag

#define L2E 1.4426950408889634f

typedef __attribute__((address_space(1))) void gvoid_t;
typedef __attribute__((address_space(3))) void lvoid_t;

__device__ __forceinline__ u16 f2bf(float f) {
  unsigned u = __builtin_bit_cast(unsigned, f);
  return (u16)((u + 0x7FFFu + ((u >> 16) & 1u)) >> 16);
}
__device__ __forceinline__ float bf2f(u16 h) {
  return __builtin_bit_cast(float, ((unsigned)h) << 16);
}
__device__ __forceinline__ f4v mfma16(s8v a, s8v b, f4v c) {
  return __builtin_amdgcn_mfma_f32_16x16x32_bf16(a, b, c, 0, 0, 0);
}
__device__ __forceinline__ float exp2fast(float x) {
#if __has_builtin(__builtin_amdgcn_exp2f)
  return __builtin_amdgcn_exp2f(x);
#else
  return exp2f(x);
#endif
}
// pack 8 f32 -> 8 bf16 via HW packed convert (RNE)
__device__ __forceinline__ s8v pack8(const float* p) {
  union { s8v v; unsigned u[4]; } r;
#pragma unroll
  for (int i = 0; i < 4; ++i)
    asm("v_cvt_pk_bf16_f32 %0, %1, %2"
        : "=v"(r.u[i])
        : "v"(p[2 * i]), "v"(p[2 * i + 1]));
  return r.v;
}
// async global->LDS, 16B per lane; LDS dest = uniform base + lane*16
__device__ __forceinline__ void stage16(const u16* g, u16* lds_arr, int slot) {
#if __has_builtin(__builtin_amdgcn_global_load_lds)
  __builtin_amdgcn_global_load_lds((gvoid_t*)(g),
      (lvoid_t*)(lds_arr + (size_t)(slot & ~63) * 8), 16, 0, 0);
#else
  *(us8*)(lds_arr + (size_t)slot * 8) = *(const us8*)g;
#endif
}

// ---------------- prep kernels ----------------
__global__ __launch_bounds__(256) void prep_x(const float* __restrict__ x,
                                              u16* __restrict__ xb) {
  int i = (blockIdx.x * 256 + threadIdx.x) * 8;
  float4 v0 = *(const float4*)(x + i);
  float4 v1 = *(const float4*)(x + i + 4);
  us8 o;
  o[0] = f2bf(v0.x); o[1] = f2bf(v0.y); o[2] = f2bf(v0.z); o[3] = f2bf(v0.w);
  o[4] = f2bf(v1.x); o[5] = f2bf(v1.y); o[6] = f2bf(v1.z); o[7] = f2bf(v1.w);
  *(us8*)(xb + i) = o;
}

// W_heads [4][512][128] f32 -> Wt_all [512 cols][512 k] bf16 (col = h*128+f)
__global__ __launch_bounds__(256) void prep_wall(const float* __restrict__ W,
                                                 u16* __restrict__ Wt) {
  int idx = blockIdx.x * 256 + threadIdx.x;  // h*65536 + k*128 + f
  int h = idx >> 16, k = (idx >> 7) & 511, f = idx & 127;
  Wt[(size_t)(h * 128 + f) * 512 + k] = f2bf(W[idx]);
}
// W_out [512][256] f32 -> Wt_out [256][512] bf16
__global__ __launch_bounds__(256) void prep_wout(const float* __restrict__ W,
                                                 u16* __restrict__ Wt) {
  int idx = blockIdx.x * 256 + threadIdx.x;  // k*256 + c
  int k = idx >> 8, c = idx & 255;
  Wt[(size_t)c * 512 + k] = f2bf(W[idx]);
}
// adj int32 [4][2048][2048] -> bitmask [4*2048][64 words]
__global__ __launch_bounds__(256) void prep_adj(const int* __restrict__ adj,
                                                unsigned* __restrict__ adjw) {
  int chunk = blockIdx.x * 4 + (threadIdx.x >> 6);
  int l = threadIdx.x & 63;
  int v = adj[(size_t)chunk * 64 + l];
  unsigned long long m = __ballot(v != 0);
  if (l == 0) {
    ((uint2*)adjw)[chunk] = make_uint2((unsigned)m, (unsigned)(m >> 32));
  }
}

// ---------------- GEMM: C^T = (A[M,512] @ B) stored as Ct[b][col][n] bf16 ----
__global__ __launch_bounds__(256) void gemm_bf16(const u16* __restrict__ A,
                                                 const u16* __restrict__ Bt,
                                                 u16* __restrict__ Ct, int CO) {
  const int K = 512, N = 2048;
  int m0 = blockIdx.x * 128;
  int n0 = blockIdx.y * 128;
  int t = threadIdx.x;
  int w = t >> 6, l = t & 63, lr = l & 15, lq = l >> 4;
  int wr = w >> 1, wc = w & 1;
  __shared__ u16 As[2][128 * 32];
  __shared__ u16 Bs[2][128 * 32];
  f4v zero4 = {0.f, 0.f, 0.f, 0.f};
  f4v acc[4][4];
#pragma unroll
  for (int i = 0; i < 4; ++i)
#pragma unroll
    for (int j = 0; j < 4; ++j) acc[i][j] = zero4;

  auto stage = [&](int buf, int kt) {
    int k0 = kt * 32;
    int row = t >> 2, ch = t & 3;
    stage16(A + (size_t)(m0 + row) * K + k0 + ch * 8, As[buf], t);
    stage16(Bt + (size_t)(n0 + row) * K + k0 + ch * 8, Bs[buf], t);
    int s2 = t + 256;
    row = s2 >> 2; ch = s2 & 3;
    stage16(A + (size_t)(m0 + row) * K + k0 + ch * 8, As[buf], s2);
    stage16(Bt + (size_t)(n0 + row) * K + k0 + ch * 8, Bs[buf], s2);
  };
  stage(0, 0);
  for (int kt = 0; kt < 16; ++kt) {
    __syncthreads();
    if (kt < 15) stage((kt + 1) & 1, kt + 1);
    const u16* as = As[kt & 1];
    const u16* bs = Bs[kt & 1];
    s8v af[4], bfr[4];
#pragma unroll
    for (int rf = 0; rf < 4; ++rf)
      af[rf] = *(const s8v*)&as[(wr * 64 + rf * 16 + lr) * 32 + lq * 8];
#pragma unroll
    for (int nf = 0; nf < 4; ++nf)
      bfr[nf] = *(const s8v*)&bs[(wc * 64 + nf * 16 + lr) * 32 + lq * 8];
#pragma unroll
    for (int rf = 0; rf < 4; ++rf)
#pragma unroll
      for (int nf = 0; nf < 4; ++nf)
        acc[rf][nf] = mfma16(af[rf], bfr[nf], acc[rf][nf]);
  }
  int bidx = m0 >> 11;
  int nr0 = m0 & 2047;
#pragma unroll
  for (int rf = 0; rf < 4; ++rf) {
#pragma unroll
    for (int nf = 0; nf < 4; ++nf) {
      int col = n0 + wc * 64 + nf * 16 + lr;
      int nr = nr0 + wr * 64 + rf * 16 + lq * 4;
      f4v a = acc[rf][nf];
      ushort4 v = make_ushort4(f2bf(a[0]), f2bf(a[1]), f2bf(a[2]), f2bf(a[3]));
      *(ushort4*)&Ct[((size_t)bidx * CO + col) * N + nr] = v;
    }
  }
}

// ---------------- f1/f2 (scaled by log2e) from Wh_t ----------------
// block: 64 n's x 4 F-chunks, LDS reduce over chunks. grid (32, 4, nH)
__global__ __launch_bounds__(256) void fkern(const u16* __restrict__ Wht,
                                             const float* __restrict__ a,
                                             float* __restrict__ f1L,
                                             float* __restrict__ f2L, int COLS,
                                             int F) {
  const int N = 2048;
  int h = blockIdx.z, b = blockIdx.y;
  int nl = threadIdx.x & 63, fc = threadIdx.x >> 6;
  int n = blockIdx.x * 64 + nl;
  int F4 = F >> 2;
  const u16* colp = Wht + ((size_t)(b * COLS + h * F + fc * F4)) * N + n;
  const float* ah = a + h * 2 * F + fc * F4;
  float a1 = 0.f, a2 = 0.f;
  for (int c = 0; c < F4; ++c) {
    float v = bf2f(colp[(size_t)c * N]);
    a1 = fmaf(v, ah[c], a1);
    a2 = fmaf(v, ah[F + c], a2);
  }
  __shared__ float r1[4][64], r2[4][64];
  r1[fc][nl] = a1;
  r2[fc][nl] = a2;
  __syncthreads();
  if (fc == 0) {
    float s1 = r1[0][nl] + r1[1][nl] + r1[2][nl] + r1[3][nl];
    float s2 = r2[0][nl] + r2[1][nl] + r2[2][nl] + r2[3][nl];
    f1L[(size_t)(h * 4 + b) * N + n] = s1 * L2E;
    f2L[(size_t)(h * 4 + b) * N + n] = s2 * L2E;
  }
}

// max over N of f2 per (h,b) row
__global__ __launch_bounds__(256) void fmax_kern(const float* __restrict__ f2L,
                                                 float* __restrict__ f2m) {
  int row = blockIdx.x;
  const float* p = f2L + (size_t)row * 2048;
  int t = threadIdx.x;
  float v = -__builtin_inff();
  for (int k = 0; k < 8; ++k) v = fmaxf(v, p[t + k * 256]);
#pragma unroll
  for (int d = 1; d < 64; d <<= 1) v = fmaxf(v, __shfl_xor(v, d));
  __shared__ float wm[4];
  if ((t & 63) == 0) wm[t >> 6] = v;
  __syncthreads();
  if (t == 0) f2m[row] = fmaxf(fmaxf(wm[0], wm[1]), fmaxf(wm[2], wm[3]));
}

// ---------------- fused GAT attention, fixed-max softmax ----------------
// block = (b, 128-col chunk, 32-row i-tile); 4 waves split j-tiles (j%4==w);
// V read direct from global (L2-resident); LDS used only for final merge.
template <int COLS, int F, int NCH, bool ELU>
__global__ __launch_bounds__(256) void attn_kernel(
    const u16* __restrict__ Wht, const float* __restrict__ f1L,
    const float* __restrict__ f2L, const float* __restrict__ f2max,
    const unsigned* __restrict__ adjw, const float* __restrict__ mask,
    void* __restrict__ outp) {
  const int N = 2048;
  // XCD-aware decode: combo p = b*NCH+ch pinned to XCD p&7 (blockIdx%8 -> XCD)
  int kb = blockIdx.x;
  int x = kb & 7, g = kb >> 3;
  int p = x + 8 * (g >> 6);
  int it = g & 63;
  int b = p / NCH, ch = p % NCH;
  int i0 = it * 32, col0 = ch * 128;
  int fh = col0 / F;  // head index for f arrays (L1: ch; L2: 0)
  int t = threadIdx.x;
  int w = t >> 6, l = t & 63, lr = l & 15, lq = l >> 4;

  const float* f1p = f1L + (size_t)(fh * 4 + b) * N + i0;
  float f1lo = f1p[lr], f1hi = f1p[lr + 16];
  const float* f2p = f2L + (size_t)(fh * 4 + b) * N;
  float f2m = f2max[fh * 4 + b];
  float su_lo = f1lo + f2m, su_hi = f1hi + f2m;
  float M_lo = fmaxf(su_lo, 0.2f * su_lo);  // upper bound on row scores
  float M_hi = fmaxf(su_hi, 0.2f * su_hi);
  const unsigned* awlo = adjw + (size_t)(b * N + i0 + lr) * 64;
  const unsigned* awhi = awlo + 16 * 64;
  const u16* vbase = Wht + (size_t)(b * COLS + col0) * N;

  f4v zero4 = {0.f, 0.f, 0.f, 0.f};
  f4v acc[2][8];
#pragma unroll
  for (int i = 0; i < 2; ++i)
#pragma unroll
    for (int j = 0; j < 8; ++j) acc[i][j] = zero4;
  float s_lo = 0.f, s_hi = 0.f;

  for (int k = 0; k < 16; ++k) {
    int jt = (k << 2) | w;
    int j0 = jt * 32;
    s8v vf[8];
#pragma unroll
    for (int nf = 0; nf < 8; ++nf)
      vf[nf] = *(const s8v*)&vbase[(size_t)(nf * 16 + lr) * N + j0 + lq * 8];
    unsigned aw_lo = awlo[jt] >> (lq * 8);
    unsigned aw_hi = awhi[jt] >> (lq * 8);
    float4 fa = *(const float4*)&f2p[j0 + lq * 8];
    float4 fb = *(const float4*)&f2p[j0 + lq * 8 + 4];
    float f2arr[8] = {fa.x, fa.y, fa.z, fa.w, fb.x, fb.y, fb.z, fb.w};
    float plo[8], phi[8];
#pragma unroll
    for (int e = 0; e < 8; ++e) {
      float s1 = f1lo + f2arr[e];
      float v1 = fmaxf(s1, 0.2f * s1);
      float p1 = exp2fast(v1 - M_lo);
      p1 = ((aw_lo >> e) & 1u) ? p1 : 0.f;
      s_lo += p1;
      plo[e] = p1;
      float s2 = f1hi + f2arr[e];
      float v2 = fmaxf(s2, 0.2f * s2);
      float p2 = exp2fast(v2 - M_hi);
      p2 = ((aw_hi >> e) & 1u) ? p2 : 0.f;
      s_hi += p2;
      phi[e] = p2;
    }
    s8v pa_lo = pack8(plo);
    s8v pa_hi = pack8(phi);
#pragma unroll
    for (int nf = 0; nf < 8; ++nf) {
      acc[0][nf] = mfma16(pa_lo, vf[nf], acc[0][nf]);
      acc[1][nf] = mfma16(pa_hi, vf[nf], acc[1][nf]);
    }
  }
  // full row sums (reduce over lq groups)
  s_lo += __shfl_xor(s_lo, 16);
  s_lo += __shfl_xor(s_lo, 32);
  s_hi += __shfl_xor(s_hi, 16);
  s_hi += __shfl_xor(s_hi, 32);

  __shared__ float ssum[4][32];
  __shared__ float accb[2][32][132];  // +4 pad: 2-way banks in merge
  if (l < 16) {
    ssum[w][lr] = s_lo;
    ssum[w][16 + lr] = s_hi;
  }
  int dst = w >> 1;
  if (w & 1) {
#pragma unroll
    for (int hi = 0; hi < 2; ++hi)
#pragma unroll
      for (int nf = 0; nf < 8; ++nf)
#pragma unroll
        for (int r = 0; r < 4; ++r)
          accb[dst][hi * 16 + lq * 4 + r][nf * 16 + lr] = acc[hi][nf][r];
  }
  __syncthreads();
  if (!(w & 1)) {
#pragma unroll
    for (int hi = 0; hi < 2; ++hi)
#pragma unroll
      for (int nf = 0; nf < 8; ++nf)
#pragma unroll
        for (int r = 0; r < 4; ++r)
          accb[dst][hi * 16 + lq * 4 + r][nf * 16 + lr] += acc[hi][nf][r];
  }
  __syncthreads();
  // final: 64 lanes x 2 cols, 4 row-groups of 8
  int c2 = (t & 63) * 2;
  int rh = (t >> 6) * 8;
#pragma unroll
  for (int rr = 0; rr < 8; ++rr) {
    int row = rh + rr;
    float S = ssum[0][row] + ssum[1][row] + ssum[2][row] + ssum[3][row];
    float inv = 1.f / fmaxf(S, 1e-30f);
    float v0 = (accb[0][row][c2] + accb[1][row][c2]) * inv;
    float v1 = (accb[0][row][c2 + 1] + accb[1][row][c2 + 1]) * inv;
    size_t obase = ((size_t)(b * N + i0 + row)) * COLS + col0 + c2;
    if constexpr (ELU) {
      v0 = v0 > 0.f ? v0 : exp2fast(v0 * L2E) - 1.f;
      v1 = v1 > 0.f ? v1 : exp2fast(v1 * L2E) - 1.f;
      unsigned pk = (unsigned)f2bf(v0) | ((unsigned)f2bf(v1) << 16);
      *(unsigned*)((u16*)outp + obase) = pk;
    } else {
      float mk = mask[b * N + i0 + row];
      float2 o = make_float2(v0 * mk, v1 * mk);
      *(float2*)((float*)outp + obase) = o;
    }
  }
}

// ---------------- pooling + final GEMM ----------------
__global__ __launch_bounds__(256) void pool1(const float* __restrict__ xout,
                                             const float* __restrict__ mask,
                                             float* __restrict__ pool,
                                             float* __restrict__ den) {
  int b = blockIdx.x >> 6, s = blockIdx.x & 63;
  int c = threadIdx.x;
  int n0 = s * 32;
  float acc = 0.f;
  for (int r = 0; r < 32; ++r)
    acc += xout[((size_t)(b * 2048 + n0 + r)) * 256 + c];
  atomicAdd(&pool[b * 256 + c], acc);
  if (c == 0) {
    float ms = 0.f;
    for (int r = 0; r < 32; ++r) ms += mask[b * 2048 + n0 + r];
    atomicAdd(&den[b], ms);
  }
}
__global__ __launch_bounds__(256) void pool2(const float* __restrict__ pool,
                                             const float* __restrict__ den,
                                             const float* __restrict__ Wp,
                                             const float* __restrict__ bp,
                                             float* __restrict__ out) {
  int b = blockIdx.x, f = threadIdx.x;
  __shared__ float pv[256];
  float inv = 1.f / (den[b] + 1e-10f);
  pv[f] = pool[b * 256 + f] * inv;
  __syncthreads();
  float acc = bp[f];
  for (int c = 0; c < 256; ++c) acc = fmaf(pv[c], Wp[c * 256 + f], acc);
  out[b * 256 + f] = fmaxf(acc, 0.f);
}

// ---------------- launcher ----------------
extern "C" void kernel_launch(void* const* d_in, const int* in_sizes, int n_in,
                              void* d_out, int out_size, void* d_ws,
                              size_t ws_size, hipStream_t stream) {
  (void)in_sizes; (void)n_in; (void)out_size; (void)ws_size;
  const float* x = (const float*)d_in[0];
  const int* adj = (const int*)d_in[1];
  const float* mask = (const float*)d_in[2];
  const float* Whds = (const float*)d_in[3];
  const float* ahds = (const float*)d_in[4];
  const float* Wout = (const float*)d_in[5];
  const float* aout = (const float*)d_in[6];
  const float* Wpool = (const float*)d_in[7];
  const float* bpool = (const float*)d_in[8];
  float* out = (float*)d_out;

  char* ws = (char*)d_ws;
  size_t off = 0;
  auto take = [&](size_t n) {
    char* p = ws + off;
    off += (n + 255) & ~(size_t)255;
    return p;
  };
  u16* xb = (u16*)take(8192ull * 512 * 2);
  u16* Wta = (u16*)take(512ull * 512 * 2);
  u16* Wto = (u16*)take(256ull * 512 * 2);
  unsigned* adjw = (unsigned*)take(4ull * 2048 * 64 * 4);
  u16* Wht = (u16*)take(4ull * 512 * 2048 * 2);
  float* f1a = (float*)take(4ull * 4 * 2048 * 4);
  float* f2a = (float*)take(4ull * 4 * 2048 * 4);
  u16* xcat = (u16*)take(8192ull * 512 * 2);
  u16* Wh2t = (u16*)take(4ull * 256 * 2048 * 2);
  float* f1b = (float*)take(4ull * 2048 * 4);
  float* f2b = (float*)take(4ull * 2048 * 4);
  float* f2ma = (float*)take(16 * 4);
  float* f2mb = (float*)take(4 * 4);
  float* pool = (float*)take(1024 * 4);
  float* den = (float*)take(256);

  prep_x<<<2048, 256, 0, stream>>>(x, xb);
  prep_wall<<<1024, 256, 0, stream>>>(Whds, Wta);
  prep_wout<<<512, 256, 0, stream>>>(Wout, Wto);
  prep_adj<<<65536, 256, 0, stream>>>(adj, adjw);
  gemm_bf16<<<dim3(64, 4), 256, 0, stream>>>(xb, Wta, Wht, 512);
  fkern<<<dim3(32, 4, 4), 256, 0, stream>>>(Wht, ahds, f1a, f2a, 512, 128);
  fmax_kern<<<16, 256, 0, stream>>>(f2a, f2ma);
  attn_kernel<512, 128, 4, true><<<1024, 256, 0, stream>>>(
      Wht, f1a, f2a, f2ma, adjw, nullptr, xcat);
  gemm_bf16<<<dim3(64, 2), 256, 0, stream>>>(xcat, Wto, Wh2t, 256);
  fkern<<<dim3(32, 4, 1), 256, 0, stream>>>(Wh2t, aout, f1b, f2b, 256, 256);
  fmax_kern<<<4, 256, 0, stream>>>(f2b, f2mb);
  attn_kernel<256, 256, 2, false><<<512, 256, 0, stream>>>(
      Wh2t, f1b, f2b, f2mb, adjw, mask, out + 1024);
  hipMemsetAsync(pool, 0, 4096 + 256, stream);
  pool1<<<256, 256, 0, stream>>>(out + 1024, mask, pool, den);
  pool2<<<4, 256, 0, stream>>>(pool, den, Wpool, bpool, out);
}